// Round 6
// baseline (4134.000 us; speedup 1.0000x reference)
//
#include <hip/hip_runtime.h>
#include <hip/hip_fp16.h>

// A-SNN forward: B=64, T=512, I=O=1024, A=3.
//   init_w1:  fp32->fp16 [ww_x;wb_x] for gemm1
//   gemm1:    XW[t*64+b][0:2048] = x @ [ww_x;wb_x]^T + bias   (MFMA 16x16x32 f16)
//   init_w2p: fragment-packed fp16 recurrent weights W2P
//   xa_proj:  XA = x @ wa_x^T + ba
//   scan:     256 WGs = 8 batch-domains x 32 col-groups; weights pinned in VGPRs
//             (K-split across 4 waves). h exchanged as TAGGED u32 ((fp16<<16)|t+1):
//             self-validating, so no producer ack / no flag ordering. Slim per-wave
//             sentinel poll gates the bulk tagged load; tags validated on the bulk;
//             Hbuf memset per launch makes stale-replay tags impossible.

#define B_ 64
#define T_ 512
#define I_ 1024
#define O_ 1024

typedef __attribute__((ext_vector_type(8))) _Float16 half8;
typedef __attribute__((ext_vector_type(4))) float f32x4;
typedef __attribute__((ext_vector_type(4))) float float4v;
typedef __attribute__((ext_vector_type(4))) unsigned int uint4v;
typedef __attribute__((ext_vector_type(2))) unsigned int uint2v;

__device__ __forceinline__ float sigm_f(float x) { return 1.f / (1.f + __expf(-x)); }
__device__ __forceinline__ float tanh_f(float x) { return 1.f - 2.f / (1.f + __expf(2.f * x)); }
__device__ __forceinline__ float h2f_bits(unsigned short u) {
    union { unsigned short s; _Float16 h; } x; x.s = u; return (float)x.h;
}

// ---------------- workspace layout (bytes) ----------------
#define WS_XW    0                 // [32768][2048] f16 = 134,217,728
#define WS_W1    134217728         // [2048][1024] f16 (dead after gemm1)
#define WS_W2P   134217728         // 2,621,440 halves = 5,242,880 B (overlays W1)
#define WS_XA    139460608         // [32768][3] f32 = 393,216
#define WS_HBUF  139853824         // [2][64][1024] u32 = 524,288 (tagged h)
#define WS_SEN   140378112         // [2][8][128] u32 = 8,192 (per-wave sentinels)
#define CLR_BYTES (524288 + 8192)
// total 140,386,304 (< proven 143,427,584)

// ======================= init: W1 =======================
__global__ void init_w1(const float* __restrict__ ww_x, const float* __restrict__ wb_x,
                        _Float16* __restrict__ W1) {
    const int total = 2048 * 1024;
    for (int idx = blockIdx.x * blockDim.x + threadIdx.x; idx < total;
         idx += gridDim.x * blockDim.x) {
        int n = idx >> 10, i = idx & 1023;
        float v = (n < 1024) ? ww_x[n * 1024 + i] : wb_x[(n - 1024) * 1024 + i];
        W1[idx] = (_Float16)v;
    }
}

// ======================= init: fragment-packed recurrent weights =======================
// idx = ((((g*4+w)*5 + tile)*8 + ktl)*64 + lane)*8 + j
// row r = tile*16 + (lane&15); k = w*256 + ktl*32 + (lane>>4)*8 + j
__global__ void init_w2p(const float* __restrict__ ww_y, const float* __restrict__ wb_y,
                         const float* __restrict__ wa_y, _Float16* __restrict__ W2P) {
    const int total = 32 * 4 * 5 * 8 * 64 * 8;  // 2,621,440
    for (int idx = blockIdx.x * blockDim.x + threadIdx.x; idx < total;
         idx += gridDim.x * blockDim.x) {
        int j = idx & 7;
        int lane = (idx >> 3) & 63;
        int ktl = (idx >> 9) & 7;
        int rest = idx >> 12;          // (g*4+w)*5 + tile
        int tile = rest % 5;
        int gw = rest / 5;
        int w = gw & 3, g = gw >> 2;
        int frow = lane & 15, fch = lane >> 4;
        int r = tile * 16 + frow;
        int k = w * 256 + ktl * 32 + fch * 8 + j;
        float v = 0.f;
        if (r < 32)      v = ww_y[(g * 32 + r) * 1024 + k];
        else if (r < 64) v = wb_y[(g * 32 + r - 32) * 1024 + k];
        else if (r < 67) v = wa_y[(r - 64) * 1024 + k];
        W2P[idx] = (_Float16)v;
    }
}

// ======================= gemm1: input projections =======================
__global__ __launch_bounds__(256) void gemm1(const float* __restrict__ x,
                                             const _Float16* __restrict__ W1,
                                             const float* __restrict__ bw,
                                             const float* __restrict__ bb,
                                             _Float16* __restrict__ XW) {
    __shared__ _Float16 At[2][128][40];
    __shared__ _Float16 Bt[2][128][40];
    const int tid = threadIdx.x;
    const int lane = tid & 63, wid = tid >> 6;
    const int wr = wid >> 1, wc = wid & 1;
    const int ntile = blockIdx.x & 15;
    const int mtile = blockIdx.x >> 4;
    const long m0 = (long)mtile * 128;
    const int n0 = ntile * 128;

    const int r = tid >> 1, hf = tid & 1;
    const int bidx = (int)((m0 + r) & 63);
    const int tt = (int)((m0 + r) >> 6);
    const float* xrow = x + ((size_t)bidx * T_ + tt) * I_ + hf * 16;
    const _Float16* brow = W1 + (size_t)(n0 + r) * 1024 + hf * 16;

    float4v av[4];
    uint4v bv[2];
    auto stage_regs = [&](int kt) {
        const float4v* pa = (const float4v*)(xrow + kt * 32);
        av[0] = pa[0]; av[1] = pa[1]; av[2] = pa[2]; av[3] = pa[3];
        const uint4v* pb = (const uint4v*)(brow + kt * 32);
        bv[0] = pb[0]; bv[1] = pb[1];
    };
    auto write_lds = [&](int buf) {
        union { _Float16 h[16]; half8 v[2]; } u;
        #pragma unroll
        for (int q = 0; q < 4; ++q)
            #pragma unroll
            for (int c = 0; c < 4; ++c) u.h[q * 4 + c] = (_Float16)av[q][c];
        half8* dA = (half8*)&At[buf][r][hf * 16];
        dA[0] = u.v[0]; dA[1] = u.v[1];
        uint4v* dB = (uint4v*)&Bt[buf][r][hf * 16];
        dB[0] = bv[0]; dB[1] = bv[1];
    };

    f32x4 acc[4][4];
    #pragma unroll
    for (int i = 0; i < 4; ++i)
        #pragma unroll
        for (int j = 0; j < 4; ++j) acc[i][j] = (f32x4){0.f, 0.f, 0.f, 0.f};

    const int frow = lane & 15, fch = lane >> 4;
    auto compute = [&](int buf) {
        half8 a[4], b[4];
        #pragma unroll
        for (int i = 0; i < 4; ++i)
            a[i] = *(const half8*)&At[buf][wr * 64 + i * 16 + frow][fch * 8];
        #pragma unroll
        for (int j = 0; j < 4; ++j)
            b[j] = *(const half8*)&Bt[buf][wc * 64 + j * 16 + frow][fch * 8];
        #pragma unroll
        for (int i = 0; i < 4; ++i)
            #pragma unroll
            for (int j = 0; j < 4; ++j)
                acc[i][j] = __builtin_amdgcn_mfma_f32_16x16x32_f16(a[i], b[j], acc[i][j], 0, 0, 0);
    };

    stage_regs(0);
    write_lds(0);
    __syncthreads();
    for (int kt = 0; kt < 32; ++kt) {
        const int cur = kt & 1;
        if (kt < 31) stage_regs(kt + 1);
        compute(cur);
        if (kt < 31) { write_lds(cur ^ 1); __syncthreads(); }
    }

    const int orow = (lane >> 4) * 4, ocol = lane & 15;
    #pragma unroll
    for (int j = 0; j < 4; ++j) {
        const int n = n0 + wc * 64 + j * 16 + ocol;
        const float bias = (n < 1024) ? bw[n] : bb[n - 1024];
        #pragma unroll
        for (int i = 0; i < 4; ++i) {
            const long mb = m0 + wr * 64 + i * 16 + orow;
            #pragma unroll
            for (int rr = 0; rr < 4; ++rr)
                XW[(size_t)(mb + rr) * 2048 + n] = (_Float16)(acc[i][j][rr] + bias);
        }
    }
}

// ======================= xa projection =======================
__global__ __launch_bounds__(256) void xa_proj(const float* __restrict__ x,
                                               const float* __restrict__ wa_x,
                                               const float* __restrict__ ba,
                                               float* __restrict__ XA) {
    const int wid = threadIdx.x >> 6, lane = threadIdx.x & 63;
    const long m = (long)blockIdx.x * 4 + wid;
    const int b = (int)(m & 63), t = (int)(m >> 6);
    const float4v* xr = (const float4v*)(x + ((size_t)b * T_ + t) * I_);
    const float4v* w0 = (const float4v*)(wa_x);
    const float4v* w1 = (const float4v*)(wa_x + 1024);
    const float4v* w2 = (const float4v*)(wa_x + 2048);
    float a0 = 0.f, a1 = 0.f, a2 = 0.f;
    #pragma unroll
    for (int j = 0; j < 4; ++j) {
        const int idx = j * 64 + lane;
        float4v xv = xr[idx];
        float4v v0 = w0[idx], v1 = w1[idx], v2 = w2[idx];
        a0 += xv[0] * v0[0] + xv[1] * v0[1] + xv[2] * v0[2] + xv[3] * v0[3];
        a1 += xv[0] * v1[0] + xv[1] * v1[1] + xv[2] * v1[2] + xv[3] * v1[3];
        a2 += xv[0] * v2[0] + xv[1] * v2[1] + xv[2] * v2[2] + xv[3] * v2[3];
    }
    #pragma unroll
    for (int mset = 32; mset >= 1; mset >>= 1) {
        a0 += __shfl_xor(a0, mset);
        a1 += __shfl_xor(a1, mset);
        a2 += __shfl_xor(a2, mset);
    }
    if (lane == 0) {
        XA[m * 3 + 0] = a0 + ba[0];
        XA[m * 3 + 1] = a1 + ba[1];
        XA[m * 3 + 2] = a2 + ba[2];
    }
}

// ======================= scan =======================
#define XOR4(v) ((v[0] ^ tg) | (v[1] ^ tg) | (v[2] ^ tg) | (v[3] ^ tg))
// af u32 word from two tagged words: [lo.h_hi, hi.h_hi]
#define PERM2(lo, hi) __builtin_amdgcn_perm((hi), (lo), 0x07060302u)
#define PACKF(dst, A, Bv) { union { unsigned u[4]; half8 h; } uu; \
    uu.u[0] = PERM2(A[0], A[1]); uu.u[1] = PERM2(A[2], A[3]); \
    uu.u[2] = PERM2(Bv[0], Bv[1]); uu.u[3] = PERM2(Bv[2], Bv[3]); dst = uu.h; }

__global__ __launch_bounds__(256, 1) void scan_kernel(
    const _Float16* __restrict__ XW, const float* __restrict__ XA,
    const _Float16* __restrict__ W2P,
    float* __restrict__ out, float* __restrict__ yfin,
    unsigned int* __restrict__ Hbuf, unsigned int* __restrict__ SEN) {
    // [par][wave][tile][col16][row8 pad12] f32
    __shared__ __align__(16) float PR[2][4][5][16][12];

    const int tid = threadIdx.x;
    const int lane = tid & 63, w = tid >> 6;
    const int d = blockIdx.x & 7, g = blockIdx.x >> 3;
    const int b0 = d * 8, n0 = g * 32;
    const int bl = tid >> 5;       // 0..7 local batch (gate layout)
    const int nn = tid & 31;       // 0..31 local col
    const int frow = lane & 15, fch = lane >> 4;
    const int hi = lane >> 4, col = lane & 15;

    // -------- recurrent weights -> registers (fragment-packed, pinned) --------
    half8 Bf[5][8];
    {
        const _Float16* wp = W2P + ((size_t)(g * 4 + w) * 40 * 64 + lane) * 8;
        #pragma unroll
        for (int tile = 0; tile < 5; ++tile)
            #pragma unroll
            for (int ktl = 0; ktl < 8; ++ktl)
                Bf[tile][ktl] = *(const half8*)(wp + (size_t)(tile * 8 + ktl) * 512);
    }
    #pragma unroll
    for (int tile = 0; tile < 5; ++tile)
        #pragma unroll
        for (int ktl = 0; ktl < 8; ++ktl)
            asm volatile("" : "+v"(Bf[tile][ktl]));   // pin in VGPRs (defeat remat)

    uint4v q0, q1, q2, q3, q4, q5, q6, q7, q8, q9, q10, q11, q12, q13, q14, q15;
    q0 = q1 = q2 = q3 = q4 = q5 = q6 = q7 = (uint4v){0u, 0u, 0u, 0u};
    q8 = q9 = q10 = q11 = q12 = q13 = q14 = q15 = (uint4v){0u, 0u, 0u, 0u};

    // gate-input prefetch pointers (per-thread)
    const unsigned short* xwp = (const unsigned short*)XW + (size_t)(b0 + bl) * 2048 + n0 + nn;
    const unsigned short* xbp = xwp + 1024;
    const float* xap = XA + (size_t)(b0 + bl) * 3;

    unsigned short c_xw = xwp[0], c_xb = xbp[0];
    float c_xa0 = xap[0], c_xa1 = xap[1], c_xa2 = xap[2];
    unsigned short n_xw = 0, n_xb = 0;
    float n_xa0 = 0.f, n_xa1 = 0.f, n_xa2 = 0.f;

    float y = 0.f;
    for (int t = 0; t < T_; ++t) {
        const int par = t & 1;
        f32x4 acc[5];
        #pragma unroll
        for (int tile = 0; tile < 5; ++tile) acc[tile] = (f32x4){0.f, 0.f, 0.f, 0.f};

        if (t > 0) {
            const int parp = (t - 1) & 1;
            const unsigned tg = (unsigned)t;   // tag of h_{t-1}
            // ---- slim sentinel poll: 8B per lane per retry ----
            {
                const unsigned* sp = SEN + ((size_t)parp * 8 + d) * 128 + (lane << 1);
                uint2v fv;
                do {
                    asm volatile("global_load_dwordx2 %0, %1, off sc0 sc1\n\t"
                                 "s_waitcnt vmcnt(0)"
                                 : "=v"(fv) : "v"(sp) : "memory");
                } while (__any((int)(fv[0] < tg || fv[1] < tg)));
            }
            // ---- bulk tagged load + validate (frow<8 lanes; retries rare) ----
            if (frow < 8) {
                const unsigned* hp = Hbuf + ((size_t)parp * 64 + b0 + frow) * 1024
                                     + w * 256 + fch * 8;
                while (true) {
                    asm volatile(
                        "global_load_dwordx4 %0, %8, off sc0 sc1\n\t"
                        "global_load_dwordx4 %1, %8, off offset:16 sc0 sc1\n\t"
                        "global_load_dwordx4 %2, %8, off offset:128 sc0 sc1\n\t"
                        "global_load_dwordx4 %3, %8, off offset:144 sc0 sc1\n\t"
                        "global_load_dwordx4 %4, %8, off offset:256 sc0 sc1\n\t"
                        "global_load_dwordx4 %5, %8, off offset:272 sc0 sc1\n\t"
                        "global_load_dwordx4 %6, %8, off offset:384 sc0 sc1\n\t"
                        "global_load_dwordx4 %7, %8, off offset:400 sc0 sc1"
                        : "=&v"(q0), "=&v"(q1), "=&v"(q2), "=&v"(q3),
                          "=&v"(q4), "=&v"(q5), "=&v"(q6), "=&v"(q7)
                        : "v"(hp) : "memory");
                    asm volatile(
                        "global_load_dwordx4 %0, %8, off offset:512 sc0 sc1\n\t"
                        "global_load_dwordx4 %1, %8, off offset:528 sc0 sc1\n\t"
                        "global_load_dwordx4 %2, %8, off offset:640 sc0 sc1\n\t"
                        "global_load_dwordx4 %3, %8, off offset:656 sc0 sc1\n\t"
                        "global_load_dwordx4 %4, %8, off offset:768 sc0 sc1\n\t"
                        "global_load_dwordx4 %5, %8, off offset:784 sc0 sc1\n\t"
                        "global_load_dwordx4 %6, %8, off offset:896 sc0 sc1\n\t"
                        "global_load_dwordx4 %7, %8, off offset:912 sc0 sc1\n\t"
                        "s_waitcnt vmcnt(0)"
                        : "=&v"(q8), "=&v"(q9), "=&v"(q10), "=&v"(q11),
                          "=&v"(q12), "=&v"(q13), "=&v"(q14), "=&v"(q15)
                        : "v"(hp) : "memory");
                    unsigned bad = (XOR4(q0) | XOR4(q1) | XOR4(q2) | XOR4(q3)
                                  | XOR4(q4) | XOR4(q5) | XOR4(q6) | XOR4(q7)
                                  | XOR4(q8) | XOR4(q9) | XOR4(q10) | XOR4(q11)
                                  | XOR4(q12) | XOR4(q13) | XOR4(q14) | XOR4(q15)) & 0xffffu;
                    if (!__any((int)bad)) break;
                }
            }
            // ---- unpack (frow>=8 lanes hold zeros) + MFMA ----
            half8 af[8];
            PACKF(af[0], q0, q1);   PACKF(af[1], q2, q3);
            PACKF(af[2], q4, q5);   PACKF(af[3], q6, q7);
            PACKF(af[4], q8, q9);   PACKF(af[5], q10, q11);
            PACKF(af[6], q12, q13); PACKF(af[7], q14, q15);
            #pragma unroll
            for (int f = 0; f < 8; ++f)
                #pragma unroll
                for (int tile = 0; tile < 5; ++tile)
                    acc[tile] = __builtin_amdgcn_mfma_f32_16x16x32_f16(af[f], Bf[tile][f],
                                                                       acc[tile], 0, 0, 0);
        }

        // next-step gate-input prefetch: issued here so it has a full step to
        // complete and never sits in a poll-side vmcnt(0) drain
        if (t + 1 < T_) {
            const size_t o = (size_t)(t + 1) * 131072;
            n_xw = xwp[o];
            n_xb = xbp[o];
            const float* xa = xap + (size_t)(t + 1) * 192;
            n_xa0 = xa[0]; n_xa1 = xa[1]; n_xa2 = xa[2];
        }

        // cross-wave K-reduce via LDS (C rows 0..7 live in lanes 0..31)
        if (t > 0 && hi < 2) {
            #pragma unroll
            for (int tile = 0; tile < 5; ++tile)
                *(f32x4*)&PR[par][w][tile][col][hi * 4] = acc[tile];
        }
        __syncthreads();

        float gw = 0.f, gb = 0.f, pav = 0.f;
        if (t > 0) {
            const int tw = nn >> 4, c = nn & 15, ac = nn & 3;
            #pragma unroll
            for (int ww = 0; ww < 4; ++ww) {
                gw += PR[par][ww][tw][c][bl];
                gb += PR[par][ww][2 + tw][c][bl];
                pav += PR[par][ww][4][ac][bl];
            }
        }
        const float pa0 = __shfl(pav, (lane & 32) + 0);
        const float pa1 = __shfl(pav, (lane & 32) + 1);
        const float pa2 = __shfl(pav, (lane & 32) + 2);

        const float wv = sigm_f(h2f_bits(c_xw) + gw);
        const float bgt = tanh_f(h2f_bits(c_xb) + gb);
        const float wa0 = sigm_f(c_xa0 + pa0);
        const float wa1 = sigm_f(c_xa1 + pa1);
        const float wa2 = sigm_f(c_xa2 + pa2);
        y = wv * y + bgt;
        y = (y >= 0.f) ? y : 0.01f * y;
        const float th = tanh_f(y);
        const float sp = (y > 20.f) ? y : __logf(1.f + __expf(y));
        const float h = tanh_f(0.1f * (y * wa0 + th * wa1 + sp * wa2));

        // ---- tagged h store: self-validating, no ack, no flag ordering ----
        {
            _Float16 hh = (_Float16)h;
            union { _Float16 x; unsigned short s; } hb; hb.x = hh;
            const unsigned hu = ((unsigned)hb.s << 16) | (unsigned)(t + 1);
            __hip_atomic_store(&Hbuf[((size_t)par * 64 + b0 + bl) * 1024 + n0 + nn], hu,
                               __ATOMIC_RELAXED, __HIP_MEMORY_SCOPE_AGENT);
        }
        // per-wave sentinel (heuristic readiness gate; correctness is in the tags)
        if (lane == 0)
            __hip_atomic_store(&SEN[((size_t)par * 8 + d) * 128 + (g << 2) + w],
                               (unsigned)(t + 1), __ATOMIC_RELAXED, __HIP_MEMORY_SCOPE_AGENT);

        // off the critical path: result store
        out[((size_t)(b0 + bl) * T_ + t) * O_ + n0 + nn] = h;

        c_xw = n_xw; c_xb = n_xb;
        c_xa0 = n_xa0; c_xa1 = n_xa1; c_xa2 = n_xa2;
    }
    yfin[(size_t)(b0 + bl) * O_ + n0 + nn] = y;
}

// ======================= launch =======================
extern "C" void kernel_launch(void* const* d_in, const int* in_sizes, int n_in,
                              void* d_out, int out_size, void* d_ws, size_t ws_size,
                              hipStream_t stream) {
    const float* x    = (const float*)d_in[0];
    const float* ww_x = (const float*)d_in[1];
    const float* ww_y = (const float*)d_in[2];
    const float* bw   = (const float*)d_in[3];
    const float* wb_x = (const float*)d_in[4];
    const float* wb_y = (const float*)d_in[5];
    const float* bb   = (const float*)d_in[6];
    const float* wa_x = (const float*)d_in[7];
    const float* wa_y = (const float*)d_in[8];
    const float* ba   = (const float*)d_in[9];

    char* ws = (char*)d_ws;
    _Float16* XW  = (_Float16*)(ws + WS_XW);
    _Float16* W1  = (_Float16*)(ws + WS_W1);
    _Float16* W2P = (_Float16*)(ws + WS_W2P);
    float* XA = (float*)(ws + WS_XA);
    unsigned int* Hbuf = (unsigned int*)(ws + WS_HBUF);
    unsigned int* SEN  = (unsigned int*)(ws + WS_SEN);

    float* out = (float*)d_out;
    float* yfin = out + (size_t)B_ * T_ * O_;

    // clear tagged h-buffer + sentinels: stale tags from prior graph replays
    // would be indistinguishable from fresh ones (tags repeat per replay)
    hipMemsetAsync(ws + WS_HBUF, 0, CLR_BYTES, stream);
    hipLaunchKernelGGL(init_w1, dim3(2048), dim3(256), 0, stream, ww_x, wb_x, W1);
    hipLaunchKernelGGL(gemm1, dim3(4096), dim3(256), 0, stream, x, W1, bw, bb, XW);
    hipLaunchKernelGGL(init_w2p, dim3(1024), dim3(256), 0, stream, ww_y, wb_y, wa_y, W2P);
    hipLaunchKernelGGL(xa_proj, dim3(8192), dim3(256), 0, stream, x, wa_x, ba, XA);
    hipLaunchKernelGGL(scan_kernel, dim3(256), dim3(256), 0, stream,
                       XW, XA, W2P, out, yfin, Hbuf, SEN);
}

// Round 7
// 3611.393 us; speedup vs baseline: 1.1447x; 1.1447x over previous
//
#include <hip/hip_runtime.h>
#include <hip/hip_fp16.h>

// A-SNN forward: B=64, T=512, I=O=1024, A=3.
//   init_w1:  fp32->fp16 [ww_x;wb_x] for gemm1
//   gemm1:    XW[t*64+b][0:2048] = x @ [ww_x;wb_x]^T + bias   (MFMA 16x16x32 f16)
//   init_w2p: fragment-packed fp16 recurrent weights W2P
//   xa_proj:  XA = x @ wa_x^T + ba
//   scan:     256 WGs = 8 batch-domains x 32 col-groups; weights pinned in VGPRs
//             (K-split across 4 waves). h exchanged as TAGGED u32 ((fp16<<16)|t+1).
//             Tight sync = per-lane samples of the DATA LINES the wave will read
//             (1 word per 128B line; a line is one coalesced wave-store, so
//             sample-fresh => line-fresh), then one bulk tagged load + validate.
//             Loose sync = per-WG domain flag (posted after the barrier, i.e.
//             after all reads) checked >= t before the overwriting store:
//             enforces skew <= 1 step => no overwrite race, no livelock.
//             Next step's first poll sample is issued BEFORE the stores and
//             waited with vmcnt(3), keeping store-acks off the critical path.

#define B_ 64
#define T_ 512
#define I_ 1024
#define O_ 1024

typedef __attribute__((ext_vector_type(8))) _Float16 half8;
typedef __attribute__((ext_vector_type(4))) float f32x4;
typedef __attribute__((ext_vector_type(4))) float float4v;
typedef __attribute__((ext_vector_type(4))) unsigned int uint4v;

__device__ __forceinline__ float sigm_f(float x) { return 1.f / (1.f + __expf(-x)); }
__device__ __forceinline__ float tanh_f(float x) { return 1.f - 2.f / (1.f + __expf(2.f * x)); }
__device__ __forceinline__ float h2f_bits(unsigned short u) {
    union { unsigned short s; _Float16 h; } x; x.s = u; return (float)x.h;
}

// ---------------- workspace layout (bytes) ----------------
#define WS_XW    0                 // [32768][2048] f16 = 134,217,728
#define WS_W1    134217728         // [2048][1024] f16 (dead after gemm1)
#define WS_W2P   134217728         // 2,621,440 halves = 5,242,880 B (overlays W1)
#define WS_XA    139460608         // [32768][3] f32 = 393,216
#define WS_HBUF  139853824         // [2][64][1024] u32 = 524,288 (tagged h)
#define WS_FLG   140378112         // [8][32] u32 = 1,024 (per-WG step flags, pad 4K)
#define CLR_BYTES (524288 + 4096)
// total < 143,427,584 (proven)

// ======================= init: W1 =======================
__global__ void init_w1(const float* __restrict__ ww_x, const float* __restrict__ wb_x,
                        _Float16* __restrict__ W1) {
    const int total = 2048 * 1024;
    for (int idx = blockIdx.x * blockDim.x + threadIdx.x; idx < total;
         idx += gridDim.x * blockDim.x) {
        int n = idx >> 10, i = idx & 1023;
        float v = (n < 1024) ? ww_x[n * 1024 + i] : wb_x[(n - 1024) * 1024 + i];
        W1[idx] = (_Float16)v;
    }
}

// ======================= init: fragment-packed recurrent weights =======================
// idx = ((((g*4+w)*5 + tile)*8 + ktl)*64 + lane)*8 + j
// row r = tile*16 + (lane&15); k = w*256 + ktl*32 + (lane>>4)*8 + j
__global__ void init_w2p(const float* __restrict__ ww_y, const float* __restrict__ wb_y,
                         const float* __restrict__ wa_y, _Float16* __restrict__ W2P) {
    const int total = 32 * 4 * 5 * 8 * 64 * 8;  // 2,621,440
    for (int idx = blockIdx.x * blockDim.x + threadIdx.x; idx < total;
         idx += gridDim.x * blockDim.x) {
        int j = idx & 7;
        int lane = (idx >> 3) & 63;
        int ktl = (idx >> 9) & 7;
        int rest = idx >> 12;          // (g*4+w)*5 + tile
        int tile = rest % 5;
        int gw = rest / 5;
        int w = gw & 3, g = gw >> 2;
        int frow = lane & 15, fch = lane >> 4;
        int r = tile * 16 + frow;
        int k = w * 256 + ktl * 32 + fch * 8 + j;
        float v = 0.f;
        if (r < 32)      v = ww_y[(g * 32 + r) * 1024 + k];
        else if (r < 64) v = wb_y[(g * 32 + r - 32) * 1024 + k];
        else if (r < 67) v = wa_y[(r - 64) * 1024 + k];
        W2P[idx] = (_Float16)v;
    }
}

// ======================= gemm1: input projections =======================
__global__ __launch_bounds__(256) void gemm1(const float* __restrict__ x,
                                             const _Float16* __restrict__ W1,
                                             const float* __restrict__ bw,
                                             const float* __restrict__ bb,
                                             _Float16* __restrict__ XW) {
    __shared__ _Float16 At[2][128][40];
    __shared__ _Float16 Bt[2][128][40];
    const int tid = threadIdx.x;
    const int lane = tid & 63, wid = tid >> 6;
    const int wr = wid >> 1, wc = wid & 1;
    const int ntile = blockIdx.x & 15;
    const int mtile = blockIdx.x >> 4;
    const long m0 = (long)mtile * 128;
    const int n0 = ntile * 128;

    const int r = tid >> 1, hf = tid & 1;
    const int bidx = (int)((m0 + r) & 63);
    const int tt = (int)((m0 + r) >> 6);
    const float* xrow = x + ((size_t)bidx * T_ + tt) * I_ + hf * 16;
    const _Float16* brow = W1 + (size_t)(n0 + r) * 1024 + hf * 16;

    float4v av[4];
    uint4v bv[2];
    auto stage_regs = [&](int kt) {
        const float4v* pa = (const float4v*)(xrow + kt * 32);
        av[0] = pa[0]; av[1] = pa[1]; av[2] = pa[2]; av[3] = pa[3];
        const uint4v* pb = (const uint4v*)(brow + kt * 32);
        bv[0] = pb[0]; bv[1] = pb[1];
    };
    auto write_lds = [&](int buf) {
        union { _Float16 h[16]; half8 v[2]; } u;
        #pragma unroll
        for (int q = 0; q < 4; ++q)
            #pragma unroll
            for (int c = 0; c < 4; ++c) u.h[q * 4 + c] = (_Float16)av[q][c];
        half8* dA = (half8*)&At[buf][r][hf * 16];
        dA[0] = u.v[0]; dA[1] = u.v[1];
        uint4v* dB = (uint4v*)&Bt[buf][r][hf * 16];
        dB[0] = bv[0]; dB[1] = bv[1];
    };

    f32x4 acc[4][4];
    #pragma unroll
    for (int i = 0; i < 4; ++i)
        #pragma unroll
        for (int j = 0; j < 4; ++j) acc[i][j] = (f32x4){0.f, 0.f, 0.f, 0.f};

    const int frow = lane & 15, fch = lane >> 4;
    auto compute = [&](int buf) {
        half8 a[4], b[4];
        #pragma unroll
        for (int i = 0; i < 4; ++i)
            a[i] = *(const half8*)&At[buf][wr * 64 + i * 16 + frow][fch * 8];
        #pragma unroll
        for (int j = 0; j < 4; ++j)
            b[j] = *(const half8*)&Bt[buf][wc * 64 + j * 16 + frow][fch * 8];
        #pragma unroll
        for (int i = 0; i < 4; ++i)
            #pragma unroll
            for (int j = 0; j < 4; ++j)
                acc[i][j] = __builtin_amdgcn_mfma_f32_16x16x32_f16(a[i], b[j], acc[i][j], 0, 0, 0);
    };

    stage_regs(0);
    write_lds(0);
    __syncthreads();
    for (int kt = 0; kt < 32; ++kt) {
        const int cur = kt & 1;
        if (kt < 31) stage_regs(kt + 1);
        compute(cur);
        if (kt < 31) { write_lds(cur ^ 1); __syncthreads(); }
    }

    const int orow = (lane >> 4) * 4, ocol = lane & 15;
    #pragma unroll
    for (int j = 0; j < 4; ++j) {
        const int n = n0 + wc * 64 + j * 16 + ocol;
        const float bias = (n < 1024) ? bw[n] : bb[n - 1024];
        #pragma unroll
        for (int i = 0; i < 4; ++i) {
            const long mb = m0 + wr * 64 + i * 16 + orow;
            #pragma unroll
            for (int rr = 0; rr < 4; ++rr)
                XW[(size_t)(mb + rr) * 2048 + n] = (_Float16)(acc[i][j][rr] + bias);
        }
    }
}

// ======================= xa projection =======================
__global__ __launch_bounds__(256) void xa_proj(const float* __restrict__ x,
                                               const float* __restrict__ wa_x,
                                               const float* __restrict__ ba,
                                               float* __restrict__ XA) {
    const int wid = threadIdx.x >> 6, lane = threadIdx.x & 63;
    const long m = (long)blockIdx.x * 4 + wid;
    const int b = (int)(m & 63), t = (int)(m >> 6);
    const float4v* xr = (const float4v*)(x + ((size_t)b * T_ + t) * I_);
    const float4v* w0 = (const float4v*)(wa_x);
    const float4v* w1 = (const float4v*)(wa_x + 1024);
    const float4v* w2 = (const float4v*)(wa_x + 2048);
    float a0 = 0.f, a1 = 0.f, a2 = 0.f;
    #pragma unroll
    for (int j = 0; j < 4; ++j) {
        const int idx = j * 64 + lane;
        float4v xv = xr[idx];
        float4v v0 = w0[idx], v1 = w1[idx], v2 = w2[idx];
        a0 += xv[0] * v0[0] + xv[1] * v0[1] + xv[2] * v0[2] + xv[3] * v0[3];
        a1 += xv[0] * v1[0] + xv[1] * v1[1] + xv[2] * v1[2] + xv[3] * v1[3];
        a2 += xv[0] * v2[0] + xv[1] * v2[1] + xv[2] * v2[2] + xv[3] * v2[3];
    }
    #pragma unroll
    for (int mset = 32; mset >= 1; mset >>= 1) {
        a0 += __shfl_xor(a0, mset);
        a1 += __shfl_xor(a1, mset);
        a2 += __shfl_xor(a2, mset);
    }
    if (lane == 0) {
        XA[m * 3 + 0] = a0 + ba[0];
        XA[m * 3 + 1] = a1 + ba[1];
        XA[m * 3 + 2] = a2 + ba[2];
    }
}

// ======================= scan =======================
#define XOR4(v) ((v[0] ^ tg) | (v[1] ^ tg) | (v[2] ^ tg) | (v[3] ^ tg))
// af u32 word from two tagged words: [lo.h_hi, hi.h_hi]
#define PERM2(lo, hi) __builtin_amdgcn_perm((hi), (lo), 0x07060302u)
#define PACKF(dst, A, Bv) { union { unsigned u[4]; half8 h; } uu; \
    uu.u[0] = PERM2(A[0], A[1]); uu.u[1] = PERM2(A[2], A[3]); \
    uu.u[2] = PERM2(Bv[0], Bv[1]); uu.u[3] = PERM2(Bv[2], Bv[3]); dst = uu.h; }

__global__ __launch_bounds__(256, 1) void scan_kernel(
    const _Float16* __restrict__ XW, const float* __restrict__ XA,
    const _Float16* __restrict__ W2P,
    float* __restrict__ out, float* __restrict__ yfin,
    unsigned int* __restrict__ Hbuf, unsigned int* __restrict__ FLG) {
    // [par][wave][tile][col16][row8 pad12] f32
    __shared__ __align__(16) float PR[2][4][5][16][12];

    const int tid = threadIdx.x;
    const int lane = tid & 63, w = tid >> 6;
    const int d = blockIdx.x & 7, g = blockIdx.x >> 3;
    const int b0 = d * 8, n0 = g * 32;
    const int bl = tid >> 5;       // 0..7 local batch (gate layout)
    const int nn = tid & 31;       // 0..31 local col
    const int frow = lane & 15, fch = lane >> 4;
    const int hi = lane >> 4, col = lane & 15;

    // -------- recurrent weights -> registers (fragment-packed, pinned) --------
    half8 Bf[5][8];
    {
        const _Float16* wp = W2P + ((size_t)(g * 4 + w) * 40 * 64 + lane) * 8;
        #pragma unroll
        for (int tile = 0; tile < 5; ++tile)
            #pragma unroll
            for (int ktl = 0; ktl < 8; ++ktl)
                Bf[tile][ktl] = *(const half8*)(wp + (size_t)(tile * 8 + ktl) * 512);
    }
    #pragma unroll
    for (int tile = 0; tile < 5; ++tile)
        #pragma unroll
        for (int ktl = 0; ktl < 8; ++ktl)
            asm volatile("" : "+v"(Bf[tile][ktl]));   // pin in VGPRs (defeat remat)

    uint4v q0, q1, q2, q3, q4, q5, q6, q7, q8, q9, q10, q11, q12, q13, q14, q15;
    q0 = q1 = q2 = q3 = q4 = q5 = q6 = q7 = (uint4v){0u, 0u, 0u, 0u};
    q8 = q9 = q10 = q11 = q12 = q13 = q14 = q15 = (uint4v){0u, 0u, 0u, 0u};

    // gate-input prefetch pointers (per-thread)
    const unsigned short* xwp = (const unsigned short*)XW + (size_t)(b0 + bl) * 2048 + n0 + nn;
    const unsigned short* xbp = xwp + 1024;
    const float* xap = XA + (size_t)(b0 + bl) * 3;

    unsigned short c_xw = xwp[0], c_xb = xbp[0];
    float c_xa0 = xap[0], c_xa1 = xap[1], c_xa2 = xap[2];
    unsigned short n_xw = 0, n_xb = 0;
    float n_xa0 = 0.f, n_xa1 = 0.f, n_xa2 = 0.f;

    // data-line sample: lane covers line (row = lane>>3, 32-col segment = lane&7)
    // of this wave's own K-slice. One tagged word certifies its whole 128B line
    // (each line is written by one coalesced wave-store on the producer side).
    const size_t smp_off = (size_t)(b0 + (lane >> 3)) * 1024 + w * 256 + (lane & 7) * 32 + 31;
    const unsigned* fp = FLG + d * 32 + (lane & 31);

    unsigned sv = 0;          // loop-carried early poll sample
    float y = 0.f;
    for (int t = 0; t < T_; ++t) {
        const int par = t & 1;
        f32x4 acc[5];
        #pragma unroll
        for (int tile = 0; tile < 5; ++tile) acc[tile] = (f32x4){0.f, 0.f, 0.f, 0.f};
        unsigned ffv = 0xffffffffu;

        if (t > 0) {
            const int parp = (t - 1) & 1;
            const unsigned tg = (unsigned)t;   // tag of h_{t-1}
            // ---- tight poll: early-issued sample waited with vmcnt(3)
            //      (3 younger ops in flight: h, out, flag stores) ----
            asm volatile("s_waitcnt vmcnt(3)" : "+v"(sv)::);
            __builtin_amdgcn_sched_barrier(0);
            if (__any((int)((sv & 0xffffu) != tg))) {
                const unsigned* smp = Hbuf + (size_t)parp * 65536 + smp_off;
                do {
                    asm volatile("global_load_dword %0, %1, off sc0 sc1\n\t"
                                 "s_waitcnt vmcnt(0)"
                                 : "=v"(sv) : "v"(smp) : "memory");
                } while (__any((int)((sv & 0xffffu) != tg)));
            }
            // ---- bulk tagged load + validate (frow<8 lanes; retries rare) ----
            if (frow < 8) {
                const unsigned* hp = Hbuf + ((size_t)parp * 64 + b0 + frow) * 1024
                                     + w * 256 + fch * 8;
                while (true) {
                    asm volatile(
                        "global_load_dwordx4 %0, %8, off sc0 sc1\n\t"
                        "global_load_dwordx4 %1, %8, off offset:16 sc0 sc1\n\t"
                        "global_load_dwordx4 %2, %8, off offset:128 sc0 sc1\n\t"
                        "global_load_dwordx4 %3, %8, off offset:144 sc0 sc1\n\t"
                        "global_load_dwordx4 %4, %8, off offset:256 sc0 sc1\n\t"
                        "global_load_dwordx4 %5, %8, off offset:272 sc0 sc1\n\t"
                        "global_load_dwordx4 %6, %8, off offset:384 sc0 sc1\n\t"
                        "global_load_dwordx4 %7, %8, off offset:400 sc0 sc1"
                        : "=&v"(q0), "=&v"(q1), "=&v"(q2), "=&v"(q3),
                          "=&v"(q4), "=&v"(q5), "=&v"(q6), "=&v"(q7)
                        : "v"(hp) : "memory");
                    asm volatile(
                        "global_load_dwordx4 %0, %8, off offset:512 sc0 sc1\n\t"
                        "global_load_dwordx4 %1, %8, off offset:528 sc0 sc1\n\t"
                        "global_load_dwordx4 %2, %8, off offset:640 sc0 sc1\n\t"
                        "global_load_dwordx4 %3, %8, off offset:656 sc0 sc1\n\t"
                        "global_load_dwordx4 %4, %8, off offset:768 sc0 sc1\n\t"
                        "global_load_dwordx4 %5, %8, off offset:784 sc0 sc1\n\t"
                        "global_load_dwordx4 %6, %8, off offset:896 sc0 sc1\n\t"
                        "global_load_dwordx4 %7, %8, off offset:912 sc0 sc1\n\t"
                        "s_waitcnt vmcnt(0)"
                        : "=&v"(q8), "=&v"(q9), "=&v"(q10), "=&v"(q11),
                          "=&v"(q12), "=&v"(q13), "=&v"(q14), "=&v"(q15)
                        : "v"(hp) : "memory");
                    unsigned bad = (XOR4(q0) | XOR4(q1) | XOR4(q2) | XOR4(q3)
                                  | XOR4(q4) | XOR4(q5) | XOR4(q6) | XOR4(q7)
                                  | XOR4(q8) | XOR4(q9) | XOR4(q10) | XOR4(q11)
                                  | XOR4(q12) | XOR4(q13) | XOR4(q14) | XOR4(q15)) & 0xffffu;
                    if (!__any((int)bad)) break;
                }
            }
            // ---- unpack (frow>=8 lanes hold zeros) + MFMA ----
            half8 af[8];
            PACKF(af[0], q0, q1);   PACKF(af[1], q2, q3);
            PACKF(af[2], q4, q5);   PACKF(af[3], q6, q7);
            PACKF(af[4], q8, q9);   PACKF(af[5], q10, q11);
            PACKF(af[6], q12, q13); PACKF(af[7], q14, q15);
            #pragma unroll
            for (int f = 0; f < 8; ++f)
                #pragma unroll
                for (int tile = 0; tile < 5; ++tile)
                    acc[tile] = __builtin_amdgcn_mfma_f32_16x16x32_f16(af[f], Bf[tile][f],
                                                                       acc[tile], 0, 0, 0);
            // loose overwrite-gate: issue domain-flag load now (monotonic =>
            // an early pass is still valid at store time)
            asm volatile("global_load_dword %0, %1, off sc0 sc1" : "=v"(ffv) : "v"(fp));
        }

        // next-step gate-input prefetch (has a full step to complete)
        if (t + 1 < T_) {
            const size_t o = (size_t)(t + 1) * 131072;
            n_xw = xwp[o];
            n_xb = xbp[o];
            const float* xa = xap + (size_t)(t + 1) * 192;
            n_xa0 = xa[0]; n_xa1 = xa[1]; n_xa2 = xa[2];
        }

        // cross-wave K-reduce via LDS (C rows 0..7 live in lanes 0..31)
        if (t > 0 && hi < 2) {
            #pragma unroll
            for (int tile = 0; tile < 5; ++tile)
                *(f32x4*)&PR[par][w][tile][col][hi * 4] = acc[tile];
        }
        __syncthreads();

        float gw = 0.f, gb = 0.f, pav = 0.f;
        if (t > 0) {
            const int tw = nn >> 4, c = nn & 15, ac = nn & 3;
            #pragma unroll
            for (int ww = 0; ww < 4; ++ww) {
                gw += PR[par][ww][tw][c][bl];
                gb += PR[par][ww][2 + tw][c][bl];
                pav += PR[par][ww][4][ac][bl];
            }
        }
        const float pa0 = __shfl(pav, (lane & 32) + 0);
        const float pa1 = __shfl(pav, (lane & 32) + 1);
        const float pa2 = __shfl(pav, (lane & 32) + 2);

        const float wv = sigm_f(h2f_bits(c_xw) + gw);
        const float bgt = tanh_f(h2f_bits(c_xb) + gb);
        const float wa0 = sigm_f(c_xa0 + pa0);
        const float wa1 = sigm_f(c_xa1 + pa1);
        const float wa2 = sigm_f(c_xa2 + pa2);
        y = wv * y + bgt;
        y = (y >= 0.f) ? y : 0.01f * y;
        const float th = tanh_f(y);
        const float sp = (y > 20.f) ? y : __logf(1.f + __expf(y));
        const float h = tanh_f(0.1f * (y * wa0 + th * wa1 + sp * wa2));

        // ---- loose overwrite-gate check: all WGs of the domain must have
        //      finished step t-1 (flag >= t) before we overwrite tag t-1 ----
        if (t > 0) {
            asm volatile("s_waitcnt vmcnt(0)" : "+v"(ffv) :: "memory");
            __builtin_amdgcn_sched_barrier(0);
            while (__any((int)(ffv < (unsigned)t))) {
                asm volatile("global_load_dword %0, %1, off sc0 sc1\n\t"
                             "s_waitcnt vmcnt(0)"
                             : "=v"(ffv) : "v"(fp) : "memory");
            }
        }

        // ---- issue next step's poll sample BEFORE the stores (vmcnt(3) pairs
        //      with exactly these 3 younger stores at the next loop top) ----
        {
            const unsigned* smpn = Hbuf + (size_t)par * 65536 + smp_off;
            asm volatile("global_load_dword %0, %1, off sc0 sc1"
                         : "=v"(sv) : "v"(smpn) : "memory");
        }
        // ---- tagged h store: self-validating (no ack needed) ----
        {
            _Float16 hh = (_Float16)h;
            union { _Float16 x; unsigned short s; } hb; hb.x = hh;
            const unsigned hu = ((unsigned)hb.s << 16) | (unsigned)(t + 1);
            __hip_atomic_store(&Hbuf[((size_t)par * 64 + b0 + bl) * 1024 + n0 + nn], hu,
                               __ATOMIC_RELAXED, __HIP_MEMORY_SCOPE_AGENT);
        }
        // result store (off critical path)
        out[((size_t)(b0 + bl) * T_ + t) * O_ + n0 + nn] = h;
        // flag post: value t+1 = "finished step t (all reads retired — barrier passed)"
        if (lane == 0)
            __hip_atomic_store((unsigned*)(FLG + d * 32 + g), (unsigned)(t + 1),
                               __ATOMIC_RELAXED, __HIP_MEMORY_SCOPE_AGENT);

        c_xw = n_xw; c_xb = n_xb;
        c_xa0 = n_xa0; c_xa1 = n_xa1; c_xa2 = n_xa2;
    }
    yfin[(size_t)(b0 + bl) * O_ + n0 + nn] = y;
}

// ======================= launch =======================
extern "C" void kernel_launch(void* const* d_in, const int* in_sizes, int n_in,
                              void* d_out, int out_size, void* d_ws, size_t ws_size,
                              hipStream_t stream) {
    const float* x    = (const float*)d_in[0];
    const float* ww_x = (const float*)d_in[1];
    const float* ww_y = (const float*)d_in[2];
    const float* bw   = (const float*)d_in[3];
    const float* wb_x = (const float*)d_in[4];
    const float* wb_y = (const float*)d_in[5];
    const float* bb   = (const float*)d_in[6];
    const float* wa_x = (const float*)d_in[7];
    const float* wa_y = (const float*)d_in[8];
    const float* ba   = (const float*)d_in[9];

    char* ws = (char*)d_ws;
    _Float16* XW  = (_Float16*)(ws + WS_XW);
    _Float16* W1  = (_Float16*)(ws + WS_W1);
    _Float16* W2P = (_Float16*)(ws + WS_W2P);
    float* XA = (float*)(ws + WS_XA);
    unsigned int* Hbuf = (unsigned int*)(ws + WS_HBUF);
    unsigned int* FLG  = (unsigned int*)(ws + WS_FLG);

    float* out = (float*)d_out;
    float* yfin = out + (size_t)B_ * T_ * O_;

    // clear tagged h-buffer + flags: stale tags from prior graph replays
    // would be indistinguishable from fresh ones (tags repeat per replay)
    hipMemsetAsync(ws + WS_HBUF, 0, CLR_BYTES, stream);
    hipLaunchKernelGGL(init_w1, dim3(2048), dim3(256), 0, stream, ww_x, wb_x, W1);
    hipLaunchKernelGGL(gemm1, dim3(4096), dim3(256), 0, stream, x, W1, bw, bb, XW);
    hipLaunchKernelGGL(init_w2p, dim3(1024), dim3(256), 0, stream, ww_y, wb_y, wa_y, W2P);
    hipLaunchKernelGGL(xa_proj, dim3(8192), dim3(256), 0, stream, x, wa_x, ba, XA);
    hipLaunchKernelGGL(scan_kernel, dim3(256), dim3(256), 0, stream,
                       XW, XA, W2P, out, yfin, Hbuf, FLG);
}

// Round 8
// 2414.014 us; speedup vs baseline: 1.7125x; 1.4960x over previous
//
#include <hip/hip_runtime.h>
#include <hip/hip_fp16.h>
#include <type_traits>

// A-SNN forward: B=64, T=512, I=O=1024, A=3.
//   init_w1:  fp32->fp16 [ww_x;wb_x] for gemm1
//   gemm1:    XW[t*64+b][0:2048] = x @ [ww_x;wb_x]^T + bias   (MFMA 16x16x32 f16)
//   init_w2p: fragment-packed fp16 recurrent weights W2P
//   xa_proj:  XA = x @ wa_x^T + ba
//   scan:     256 WGs = 8 batch-domains x 32 col-groups; weights pinned in VGPRs
//             (K-split across 4 waves). h exchanged as TAGGED u32 ((fp16<<16)|t+1),
//             slim per-wave flag poll (contiguous 512B) for detection, bulk load
//             validated by tags (no producer ack). NEW: per-domain XCD-locality
//             PROBE at startup — if a domain's 32 WGs share an L2 (verified by
//             observing 8 monotone sc0 updates from every peer), the whole
//             rendezvous runs at sc0/L2 speed (~200cy hops); otherwise falls back
//             to sc1/L3 (always-correct). Mode is all-reduced via sc1 so all WGs
//             of a domain agree; numerics are identical in both modes.

#define B_ 64
#define T_ 512
#define I_ 1024
#define O_ 1024

typedef __attribute__((ext_vector_type(8))) _Float16 half8;
typedef __attribute__((ext_vector_type(4))) float f32x4;
typedef __attribute__((ext_vector_type(4))) float float4v;
typedef __attribute__((ext_vector_type(4))) unsigned int uint4v;
typedef __attribute__((ext_vector_type(2))) unsigned int uint2v;

__device__ __forceinline__ float sigm_f(float x) { return 1.f / (1.f + __expf(-x)); }
__device__ __forceinline__ float tanh_f(float x) { return 1.f - 2.f / (1.f + __expf(2.f * x)); }
__device__ __forceinline__ float h2f_bits(unsigned short u) {
    union { unsigned short s; _Float16 h; } x; x.s = u; return (float)x.h;
}

// ---------------- workspace layout (bytes) ----------------
#define WS_XW    0                 // [32768][2048] f16 = 134,217,728
#define WS_W1    134217728         // [2048][1024] f16 (dead after gemm1)
#define WS_W2P   134217728         // 2,621,440 halves = 5,242,880 B (overlays W1)
#define WS_XA    139460608         // [32768][3] f32 = 393,216
#define WS_HBUF  139853824         // [2][64][1024] u32 = 524,288 (tagged h)
#define WS_FLG   140378112         // [2][8][128] u32 = 8,192 (per-wave step flags)
#define WS_PRB   140386304         // [8][32] x 128B probe lines = 32,768
#define WS_RES   140419072         // [8][32] u32 = 1,024 (probe results)
#define CLR_BYTES (524288 + 8192 + 32768 + 1024)
// total 140,420,096 (< proven 143,427,584)

// ======================= init: W1 =======================
__global__ void init_w1(const float* __restrict__ ww_x, const float* __restrict__ wb_x,
                        _Float16* __restrict__ W1) {
    const int total = 2048 * 1024;
    for (int idx = blockIdx.x * blockDim.x + threadIdx.x; idx < total;
         idx += gridDim.x * blockDim.x) {
        int n = idx >> 10, i = idx & 1023;
        float v = (n < 1024) ? ww_x[n * 1024 + i] : wb_x[(n - 1024) * 1024 + i];
        W1[idx] = (_Float16)v;
    }
}

// ======================= init: fragment-packed recurrent weights =======================
// idx = ((((g*4+w)*5 + tile)*8 + ktl)*64 + lane)*8 + j
// row r = tile*16 + (lane&15); k = w*256 + ktl*32 + (lane>>4)*8 + j
__global__ void init_w2p(const float* __restrict__ ww_y, const float* __restrict__ wb_y,
                         const float* __restrict__ wa_y, _Float16* __restrict__ W2P) {
    const int total = 32 * 4 * 5 * 8 * 64 * 8;  // 2,621,440
    for (int idx = blockIdx.x * blockDim.x + threadIdx.x; idx < total;
         idx += gridDim.x * blockDim.x) {
        int j = idx & 7;
        int lane = (idx >> 3) & 63;
        int ktl = (idx >> 9) & 7;
        int rest = idx >> 12;          // (g*4+w)*5 + tile
        int tile = rest % 5;
        int gw = rest / 5;
        int w = gw & 3, g = gw >> 2;
        int frow = lane & 15, fch = lane >> 4;
        int r = tile * 16 + frow;
        int k = w * 256 + ktl * 32 + fch * 8 + j;
        float v = 0.f;
        if (r < 32)      v = ww_y[(g * 32 + r) * 1024 + k];
        else if (r < 64) v = wb_y[(g * 32 + r - 32) * 1024 + k];
        else if (r < 67) v = wa_y[(r - 64) * 1024 + k];
        W2P[idx] = (_Float16)v;
    }
}

// ======================= gemm1: input projections =======================
__global__ __launch_bounds__(256) void gemm1(const float* __restrict__ x,
                                             const _Float16* __restrict__ W1,
                                             const float* __restrict__ bw,
                                             const float* __restrict__ bb,
                                             _Float16* __restrict__ XW) {
    __shared__ _Float16 At[2][128][40];
    __shared__ _Float16 Bt[2][128][40];
    const int tid = threadIdx.x;
    const int lane = tid & 63, wid = tid >> 6;
    const int wr = wid >> 1, wc = wid & 1;
    const int ntile = blockIdx.x & 15;
    const int mtile = blockIdx.x >> 4;
    const long m0 = (long)mtile * 128;
    const int n0 = ntile * 128;

    const int r = tid >> 1, hf = tid & 1;
    const int bidx = (int)((m0 + r) & 63);
    const int tt = (int)((m0 + r) >> 6);
    const float* xrow = x + ((size_t)bidx * T_ + tt) * I_ + hf * 16;
    const _Float16* brow = W1 + (size_t)(n0 + r) * 1024 + hf * 16;

    float4v av[4];
    uint4v bv[2];
    auto stage_regs = [&](int kt) {
        const float4v* pa = (const float4v*)(xrow + kt * 32);
        av[0] = pa[0]; av[1] = pa[1]; av[2] = pa[2]; av[3] = pa[3];
        const uint4v* pb = (const uint4v*)(brow + kt * 32);
        bv[0] = pb[0]; bv[1] = pb[1];
    };
    auto write_lds = [&](int buf) {
        union { _Float16 h[16]; half8 v[2]; } u;
        #pragma unroll
        for (int q = 0; q < 4; ++q)
            #pragma unroll
            for (int c = 0; c < 4; ++c) u.h[q * 4 + c] = (_Float16)av[q][c];
        half8* dA = (half8*)&At[buf][r][hf * 16];
        dA[0] = u.v[0]; dA[1] = u.v[1];
        uint4v* dB = (uint4v*)&Bt[buf][r][hf * 16];
        dB[0] = bv[0]; dB[1] = bv[1];
    };

    f32x4 acc[4][4];
    #pragma unroll
    for (int i = 0; i < 4; ++i)
        #pragma unroll
        for (int j = 0; j < 4; ++j) acc[i][j] = (f32x4){0.f, 0.f, 0.f, 0.f};

    const int frow = lane & 15, fch = lane >> 4;
    auto compute = [&](int buf) {
        half8 a[4], b[4];
        #pragma unroll
        for (int i = 0; i < 4; ++i)
            a[i] = *(const half8*)&At[buf][wr * 64 + i * 16 + frow][fch * 8];
        #pragma unroll
        for (int j = 0; j < 4; ++j)
            b[j] = *(const half8*)&Bt[buf][wc * 64 + j * 16 + frow][fch * 8];
        #pragma unroll
        for (int i = 0; i < 4; ++i)
            #pragma unroll
            for (int j = 0; j < 4; ++j)
                acc[i][j] = __builtin_amdgcn_mfma_f32_16x16x32_f16(a[i], b[j], acc[i][j], 0, 0, 0);
    };

    stage_regs(0);
    write_lds(0);
    __syncthreads();
    for (int kt = 0; kt < 32; ++kt) {
        const int cur = kt & 1;
        if (kt < 31) stage_regs(kt + 1);
        compute(cur);
        if (kt < 31) { write_lds(cur ^ 1); __syncthreads(); }
    }

    const int orow = (lane >> 4) * 4, ocol = lane & 15;
    #pragma unroll
    for (int j = 0; j < 4; ++j) {
        const int n = n0 + wc * 64 + j * 16 + ocol;
        const float bias = (n < 1024) ? bw[n] : bb[n - 1024];
        #pragma unroll
        for (int i = 0; i < 4; ++i) {
            const long mb = m0 + wr * 64 + i * 16 + orow;
            #pragma unroll
            for (int rr = 0; rr < 4; ++rr)
                XW[(size_t)(mb + rr) * 2048 + n] = (_Float16)(acc[i][j][rr] + bias);
        }
    }
}

// ======================= xa projection =======================
__global__ __launch_bounds__(256) void xa_proj(const float* __restrict__ x,
                                               const float* __restrict__ wa_x,
                                               const float* __restrict__ ba,
                                               float* __restrict__ XA) {
    const int wid = threadIdx.x >> 6, lane = threadIdx.x & 63;
    const long m = (long)blockIdx.x * 4 + wid;
    const int b = (int)(m & 63), t = (int)(m >> 6);
    const float4v* xr = (const float4v*)(x + ((size_t)b * T_ + t) * I_);
    const float4v* w0 = (const float4v*)(wa_x);
    const float4v* w1 = (const float4v*)(wa_x + 1024);
    const float4v* w2 = (const float4v*)(wa_x + 2048);
    float a0 = 0.f, a1 = 0.f, a2 = 0.f;
    #pragma unroll
    for (int j = 0; j < 4; ++j) {
        const int idx = j * 64 + lane;
        float4v xv = xr[idx];
        float4v v0 = w0[idx], v1 = w1[idx], v2 = w2[idx];
        a0 += xv[0] * v0[0] + xv[1] * v0[1] + xv[2] * v0[2] + xv[3] * v0[3];
        a1 += xv[0] * v1[0] + xv[1] * v1[1] + xv[2] * v1[2] + xv[3] * v1[3];
        a2 += xv[0] * v2[0] + xv[1] * v2[1] + xv[2] * v2[2] + xv[3] * v2[3];
    }
    #pragma unroll
    for (int mset = 32; mset >= 1; mset >>= 1) {
        a0 += __shfl_xor(a0, mset);
        a1 += __shfl_xor(a1, mset);
        a2 += __shfl_xor(a2, mset);
    }
    if (lane == 0) {
        XA[m * 3 + 0] = a0 + ba[0];
        XA[m * 3 + 1] = a1 + ba[1];
        XA[m * 3 + 2] = a2 + ba[2];
    }
}

// ======================= scan =======================
#define XOR4(v) ((v[0] ^ tg) | (v[1] ^ tg) | (v[2] ^ tg) | (v[3] ^ tg))
// af u32 word from two tagged words: [lo.h_hi, hi.h_hi]
#define PERM2(lo, hi) __builtin_amdgcn_perm((hi), (lo), 0x07060302u)
#define PACKF(dst, A, Bv) { union { unsigned u[4]; half8 h; } uu; \
    uu.u[0] = PERM2(A[0], A[1]); uu.u[1] = PERM2(A[2], A[3]); \
    uu.u[2] = PERM2(Bv[0], Bv[1]); uu.u[3] = PERM2(Bv[2], Bv[3]); dst = uu.h; }

__global__ __launch_bounds__(256, 1) void scan_kernel(
    const _Float16* __restrict__ XW, const float* __restrict__ XA,
    const _Float16* __restrict__ W2P,
    float* __restrict__ out, float* __restrict__ yfin,
    unsigned int* __restrict__ Hbuf, unsigned int* __restrict__ FLG,
    unsigned int* __restrict__ PRB, unsigned int* __restrict__ RES) {
    // [par][wave][tile][col16][row8 pad12] f32
    __shared__ __align__(16) float PR[2][4][5][16][12];
    __shared__ int fast_s;

    const int tid = threadIdx.x;
    const int lane = tid & 63, w = tid >> 6;
    const int d = blockIdx.x & 7, g = blockIdx.x >> 3;
    const int b0 = d * 8, n0 = g * 32;
    const int bl = tid >> 5;       // 0..7 local batch (gate layout)
    const int nn = tid & 31;       // 0..31 local col
    const int frow = lane & 15, fch = lane >> 4;
    const int hi = lane >> 4, col = lane & 15;

    // -------- recurrent weights -> registers (fragment-packed, pinned) --------
    half8 Bf[5][8];
    {
        const _Float16* wp = W2P + ((size_t)(g * 4 + w) * 40 * 64 + lane) * 8;
        #pragma unroll
        for (int tile = 0; tile < 5; ++tile)
            #pragma unroll
            for (int ktl = 0; ktl < 8; ++ktl)
                Bf[tile][ktl] = *(const half8*)(wp + (size_t)(tile * 8 + ktl) * 512);
    }
    #pragma unroll
    for (int tile = 0; tile < 5; ++tile)
        #pragma unroll
        for (int ktl = 0; ktl < 8; ++ktl)
            asm volatile("" : "+v"(Bf[tile][ktl]));   // pin in VGPRs

    // ---------------- XCD-locality probe ----------------
    // FAST iff every peer's sc0 counter stream (8 monotone updates on a private
    // 128B line) is observed — proves shared (coherent) L2. sc1 all-reduce of
    // the verdict guarantees a domain-consistent mode. Timeout => SAFE.
    {
        if (w == 0) {
            unsigned* myslot = PRB + (size_t)(d * 32 + g) * 32;
            const unsigned* pslot = PRB + (size_t)(d * 32 + (lane & 31)) * 32;
            unsigned ok = 0, k = 1;
            const unsigned long long t0 = __builtin_amdgcn_s_memrealtime();
            int it = 0;
            while (true) {
                if (lane == 0 && k <= 8u && (it & 3) == 0) {
                    asm volatile("global_store_dword %0, %1, off sc0"
                                 :: "v"(myslot), "v"(k) : "memory");
                    ++k;
                }
                unsigned v;
                asm volatile("global_load_dword %0, %1, off sc0\n\ts_waitcnt vmcnt(0)"
                             : "=v"(v) : "v"(pslot) : "memory");
                if (__all((int)(v >= 8u))) { ok = 1; break; }
                if (__builtin_amdgcn_s_memrealtime() - t0 > 5000ull) { ok = 0; break; }
                ++it;
            }
            if (lane == 0) {
                const unsigned pubv = ok ? 2u : 1u;
                asm volatile("global_store_dword %0, %1, off sc0 sc1"
                             :: "v"(RES + d * 32 + g), "v"(pubv) : "memory");
            }
            const unsigned* rp = RES + d * 32 + (lane & 31);
            int allfast;
            while (true) {
                unsigned v;
                asm volatile("global_load_dword %0, %1, off sc0 sc1\n\ts_waitcnt vmcnt(0)"
                             : "=v"(v) : "v"(rp) : "memory");
                if (__all((int)(v != 0u))) { allfast = __all((int)(v == 2u)); break; }
            }
            if (lane == 0) fast_s = allfast;
        }
        __syncthreads();
    }
    const int fast = fast_s;

    uint4v q0, q1, q2, q3, q4, q5, q6, q7, q8, q9, q10, q11, q12, q13, q14, q15;
    q0 = q1 = q2 = q3 = q4 = q5 = q6 = q7 = (uint4v){0u, 0u, 0u, 0u};
    q8 = q9 = q10 = q11 = q12 = q13 = q14 = q15 = (uint4v){0u, 0u, 0u, 0u};

    // gate-input prefetch pointers (per-thread)
    const unsigned short* xwp = (const unsigned short*)XW + (size_t)(b0 + bl) * 2048 + n0 + nn;
    const unsigned short* xbp = xwp + 1024;
    const float* xap = XA + (size_t)(b0 + bl) * 3;

    unsigned short c_xw = xwp[0], c_xb = xbp[0];
    float c_xa0 = xap[0], c_xa1 = xap[1], c_xa2 = xap[2];
    unsigned short n_xw = 0, n_xb = 0;
    float n_xa0 = 0.f, n_xa1 = 0.f, n_xa2 = 0.f;

    auto run = [&](auto fastc) {
        constexpr bool FAST = decltype(fastc)::value;
        float y = 0.f;
        for (int t = 0; t < T_; ++t) {
            const int par = t & 1;
            f32x4 acc[5];
            #pragma unroll
            for (int tile = 0; tile < 5; ++tile) acc[tile] = (f32x4){0.f, 0.f, 0.f, 0.f};

            if (t > 0) {
                const int parp = (t - 1) & 1;
                const unsigned tg = (unsigned)t;   // tag of h_{t-1}
                // ---- slim flag poll: contiguous 512B per wave per retry ----
                {
                    const unsigned* fp2 = FLG + ((size_t)parp * 8 + d) * 128 + (lane << 1);
                    uint2v fv;
                    do {
                        if constexpr (FAST)
                            asm volatile("global_load_dwordx2 %0, %1, off sc0\n\t"
                                         "s_waitcnt vmcnt(0)"
                                         : "=v"(fv) : "v"(fp2) : "memory");
                        else
                            asm volatile("global_load_dwordx2 %0, %1, off sc0 sc1\n\t"
                                         "s_waitcnt vmcnt(0)"
                                         : "=v"(fv) : "v"(fp2) : "memory");
                    } while (__any((int)(fv[0] < tg || fv[1] < tg)));
                }
                // ---- bulk tagged load + validate (frow<8 lanes; retry rare) ----
                if (frow < 8) {
                    const unsigned* hp = Hbuf + ((size_t)parp * 64 + b0 + frow) * 1024
                                         + w * 256 + fch * 8;
                    while (true) {
                        if constexpr (FAST) {
                            asm volatile(
                                "global_load_dwordx4 %0, %8, off sc0\n\t"
                                "global_load_dwordx4 %1, %8, off offset:16 sc0\n\t"
                                "global_load_dwordx4 %2, %8, off offset:128 sc0\n\t"
                                "global_load_dwordx4 %3, %8, off offset:144 sc0\n\t"
                                "global_load_dwordx4 %4, %8, off offset:256 sc0\n\t"
                                "global_load_dwordx4 %5, %8, off offset:272 sc0\n\t"
                                "global_load_dwordx4 %6, %8, off offset:384 sc0\n\t"
                                "global_load_dwordx4 %7, %8, off offset:400 sc0"
                                : "=&v"(q0), "=&v"(q1), "=&v"(q2), "=&v"(q3),
                                  "=&v"(q4), "=&v"(q5), "=&v"(q6), "=&v"(q7)
                                : "v"(hp) : "memory");
                            asm volatile(
                                "global_load_dwordx4 %0, %8, off offset:512 sc0\n\t"
                                "global_load_dwordx4 %1, %8, off offset:528 sc0\n\t"
                                "global_load_dwordx4 %2, %8, off offset:640 sc0\n\t"
                                "global_load_dwordx4 %3, %8, off offset:656 sc0\n\t"
                                "global_load_dwordx4 %4, %8, off offset:768 sc0\n\t"
                                "global_load_dwordx4 %5, %8, off offset:784 sc0\n\t"
                                "global_load_dwordx4 %6, %8, off offset:896 sc0\n\t"
                                "global_load_dwordx4 %7, %8, off offset:912 sc0\n\t"
                                "s_waitcnt vmcnt(0)"
                                : "=&v"(q8), "=&v"(q9), "=&v"(q10), "=&v"(q11),
                                  "=&v"(q12), "=&v"(q13), "=&v"(q14), "=&v"(q15)
                                : "v"(hp) : "memory");
                        } else {
                            asm volatile(
                                "global_load_dwordx4 %0, %8, off sc0 sc1\n\t"
                                "global_load_dwordx4 %1, %8, off offset:16 sc0 sc1\n\t"
                                "global_load_dwordx4 %2, %8, off offset:128 sc0 sc1\n\t"
                                "global_load_dwordx4 %3, %8, off offset:144 sc0 sc1\n\t"
                                "global_load_dwordx4 %4, %8, off offset:256 sc0 sc1\n\t"
                                "global_load_dwordx4 %5, %8, off offset:272 sc0 sc1\n\t"
                                "global_load_dwordx4 %6, %8, off offset:384 sc0 sc1\n\t"
                                "global_load_dwordx4 %7, %8, off offset:400 sc0 sc1"
                                : "=&v"(q0), "=&v"(q1), "=&v"(q2), "=&v"(q3),
                                  "=&v"(q4), "=&v"(q5), "=&v"(q6), "=&v"(q7)
                                : "v"(hp) : "memory");
                            asm volatile(
                                "global_load_dwordx4 %0, %8, off offset:512 sc0 sc1\n\t"
                                "global_load_dwordx4 %1, %8, off offset:528 sc0 sc1\n\t"
                                "global_load_dwordx4 %2, %8, off offset:640 sc0 sc1\n\t"
                                "global_load_dwordx4 %3, %8, off offset:656 sc0 sc1\n\t"
                                "global_load_dwordx4 %4, %8, off offset:768 sc0 sc1\n\t"
                                "global_load_dwordx4 %5, %8, off offset:784 sc0 sc1\n\t"
                                "global_load_dwordx4 %6, %8, off offset:896 sc0 sc1\n\t"
                                "global_load_dwordx4 %7, %8, off offset:912 sc0 sc1\n\t"
                                "s_waitcnt vmcnt(0)"
                                : "=&v"(q8), "=&v"(q9), "=&v"(q10), "=&v"(q11),
                                  "=&v"(q12), "=&v"(q13), "=&v"(q14), "=&v"(q15)
                                : "v"(hp) : "memory");
                        }
                        unsigned bad = (XOR4(q0) | XOR4(q1) | XOR4(q2) | XOR4(q3)
                                      | XOR4(q4) | XOR4(q5) | XOR4(q6) | XOR4(q7)
                                      | XOR4(q8) | XOR4(q9) | XOR4(q10) | XOR4(q11)
                                      | XOR4(q12) | XOR4(q13) | XOR4(q14) | XOR4(q15)) & 0xffffu;
                        if (!__any((int)bad)) break;
                    }
                }
            }

            // next-step gate-input prefetch: issued mid-step so the next poll's
            // vmcnt(0) never drains an in-flight HBM load
            if (t + 1 < T_) {
                const size_t o = (size_t)(t + 1) * 131072;
                n_xw = xwp[o];
                n_xb = xbp[o];
                const float* xa = xap + (size_t)(t + 1) * 192;
                n_xa0 = xa[0]; n_xa1 = xa[1]; n_xa2 = xa[2];
            }

            if (t > 0) {
                // ---- unpack (frow>=8 lanes hold zeros) + MFMA ----
                half8 af[8];
                PACKF(af[0], q0, q1);   PACKF(af[1], q2, q3);
                PACKF(af[2], q4, q5);   PACKF(af[3], q6, q7);
                PACKF(af[4], q8, q9);   PACKF(af[5], q10, q11);
                PACKF(af[6], q12, q13); PACKF(af[7], q14, q15);
                #pragma unroll
                for (int f = 0; f < 8; ++f)
                    #pragma unroll
                    for (int tile = 0; tile < 5; ++tile)
                        acc[tile] = __builtin_amdgcn_mfma_f32_16x16x32_f16(af[f], Bf[tile][f],
                                                                           acc[tile], 0, 0, 0);
            }

            // cross-wave K-reduce via LDS (C rows 0..7 live in lanes 0..31)
            if (t > 0 && hi < 2) {
                #pragma unroll
                for (int tile = 0; tile < 5; ++tile)
                    *(f32x4*)&PR[par][w][tile][col][hi * 4] = acc[tile];
            }
            __syncthreads();

            float gw = 0.f, gb = 0.f, pav = 0.f;
            if (t > 0) {
                const int tw = nn >> 4, c = nn & 15, ac = nn & 3;
                #pragma unroll
                for (int ww = 0; ww < 4; ++ww) {
                    gw += PR[par][ww][tw][c][bl];
                    gb += PR[par][ww][2 + tw][c][bl];
                    pav += PR[par][ww][4][ac][bl];
                }
            }
            const float pa0 = __shfl(pav, (lane & 32) + 0);
            const float pa1 = __shfl(pav, (lane & 32) + 1);
            const float pa2 = __shfl(pav, (lane & 32) + 2);

            const float wv = sigm_f(h2f_bits(c_xw) + gw);
            const float bgt = tanh_f(h2f_bits(c_xb) + gb);
            const float wa0 = sigm_f(c_xa0 + pa0);
            const float wa1 = sigm_f(c_xa1 + pa1);
            const float wa2 = sigm_f(c_xa2 + pa2);
            y = wv * y + bgt;
            y = (y >= 0.f) ? y : 0.01f * y;
            const float th = tanh_f(y);
            const float sp = (y > 20.f) ? y : __logf(1.f + __expf(y));
            const float h = tanh_f(0.1f * (y * wa0 + th * wa1 + sp * wa2));

            // ---- tagged h store (self-validating; no ack) ----
            {
                _Float16 hh = (_Float16)h;
                union { _Float16 x; unsigned short s; } hb; hb.x = hh;
                const unsigned hu = ((unsigned)hb.s << 16) | (unsigned)(t + 1);
                unsigned* ha = Hbuf + ((size_t)par * 64 + b0 + bl) * 1024 + n0 + nn;
                if constexpr (FAST)
                    asm volatile("global_store_dword %0, %1, off sc0"
                                 :: "v"(ha), "v"(hu) : "memory");
                else
                    asm volatile("global_store_dword %0, %1, off sc0 sc1"
                                 :: "v"(ha), "v"(hu) : "memory");
            }
            // per-wave flag: value t+1 = "finished step t" (reads retired by dataflow)
            if (lane == 0) {
                unsigned* fa = FLG + ((size_t)par * 8 + d) * 128 + (g << 2) + w;
                const unsigned fvv = (unsigned)(t + 1);
                if constexpr (FAST)
                    asm volatile("global_store_dword %0, %1, off sc0"
                                 :: "v"(fa), "v"(fvv) : "memory");
                else
                    asm volatile("global_store_dword %0, %1, off sc0 sc1"
                                 :: "v"(fa), "v"(fvv) : "memory");
            }
            // result store (off critical path)
            out[((size_t)(b0 + bl) * T_ + t) * O_ + n0 + nn] = h;

            c_xw = n_xw; c_xb = n_xb;
            c_xa0 = n_xa0; c_xa1 = n_xa1; c_xa2 = n_xa2;

            #pragma unroll
            for (int tile = 0; tile < 5; ++tile)
                #pragma unroll
                for (int ktl = 0; ktl < 8; ++ktl)
                    asm volatile("" : "+v"(Bf[tile][ktl]));   // keep resident across steps
        }
        yfin[(size_t)(b0 + bl) * O_ + n0 + nn] = y;
    };

    if (fast) run(std::integral_constant<bool, true>{});
    else      run(std::integral_constant<bool, false>{});
}

// ======================= launch =======================
extern "C" void kernel_launch(void* const* d_in, const int* in_sizes, int n_in,
                              void* d_out, int out_size, void* d_ws, size_t ws_size,
                              hipStream_t stream) {
    const float* x    = (const float*)d_in[0];
    const float* ww_x = (const float*)d_in[1];
    const float* ww_y = (const float*)d_in[2];
    const float* bw   = (const float*)d_in[3];
    const float* wb_x = (const float*)d_in[4];
    const float* wb_y = (const float*)d_in[5];
    const float* bb   = (const float*)d_in[6];
    const float* wa_x = (const float*)d_in[7];
    const float* wa_y = (const float*)d_in[8];
    const float* ba   = (const float*)d_in[9];

    char* ws = (char*)d_ws;
    _Float16* XW  = (_Float16*)(ws + WS_XW);
    _Float16* W1  = (_Float16*)(ws + WS_W1);
    _Float16* W2P = (_Float16*)(ws + WS_W2P);
    float* XA = (float*)(ws + WS_XA);
    unsigned int* Hbuf = (unsigned int*)(ws + WS_HBUF);
    unsigned int* FLG  = (unsigned int*)(ws + WS_FLG);
    unsigned int* PRB  = (unsigned int*)(ws + WS_PRB);
    unsigned int* RES  = (unsigned int*)(ws + WS_RES);

    float* out = (float*)d_out;
    float* yfin = out + (size_t)B_ * T_ * O_;

    // clear tagged h-buffer + flags + probe state (stale tags/probe values from
    // prior graph replays would alias fresh ones)
    hipMemsetAsync(ws + WS_HBUF, 0, CLR_BYTES, stream);
    hipLaunchKernelGGL(init_w1, dim3(2048), dim3(256), 0, stream, ww_x, wb_x, W1);
    hipLaunchKernelGGL(gemm1, dim3(4096), dim3(256), 0, stream, x, W1, bw, bb, XW);
    hipLaunchKernelGGL(init_w2p, dim3(1024), dim3(256), 0, stream, ww_y, wb_y, wa_y, W2P);
    hipLaunchKernelGGL(xa_proj, dim3(8192), dim3(256), 0, stream, x, wa_x, ba, XA);
    hipLaunchKernelGGL(scan_kernel, dim3(256), dim3(256), 0, stream,
                       XW, XA, W2P, out, yfin, Hbuf, FLG, PRB, RES);
}